// Round 9
// baseline (255.177 us; speedup 1.0000x reference)
//
#include <hip/hip_runtime.h>
#include <hip/hip_bf16.h>
#include <math.h>

#define BB 16384
#define DD 768
#define MPAD 16640             // 16384 + 84 table rows + zero pad to 130*128
#define FB 32                  // rows per fused block

typedef __attribute__((ext_vector_type(8))) short bf16x8;
typedef __attribute__((ext_vector_type(4))) float f32x4;

// Static device scratch — referenced ONLY from device code.
__device__ short g_Abf[(size_t)MPAD * DD];          // bf16 feats
__device__ short g_W[(size_t)2304 * DD];            // bf16 in_proj_w (Wq|Wk|Wv rows)
__device__ short g_WoutBf[(size_t)DD * DD];         // bf16 out_proj_w
__device__ short g_qkv[(size_t)MPAD * 2304];        // bf16 GEMM1 out: q|k|v per row (no bias)
__device__ float g_maxabs;

__device__ inline unsigned short f2bf(float x) {
    union { float f; unsigned u; } v; v.f = x;
    unsigned r = v.u + 0x7fffu + ((v.u >> 16) & 1u);
    return (unsigned short)(r >> 16);
}
__device__ inline float bf2f(unsigned short h) {
    union { unsigned u; float f; } v; v.u = ((unsigned)h) << 16;
    return v.f;
}

__device__ inline float gelu_exact(float x) {
    return 0.5f * x * (1.0f + erff(x * 0.70710678118654752440f));
}

__device__ inline float block_sum256(float v, float* sbuf) {
    #pragma unroll
    for (int o = 32; o; o >>= 1) v += __shfl_xor(v, o);
    __syncthreads();
    if ((threadIdx.x & 63) == 0) sbuf[threadIdx.x >> 6] = v;
    __syncthreads();
    return sbuf[0] + sbuf[1] + sbuf[2] + sbuf[3];
}

// single block, 1024 threads: max|x| -> g_maxabs
__global__ __launch_bounds__(1024) void k_absmax(const float* __restrict__ number) {
    const float4* n4 = reinterpret_cast<const float4*>(number);
    float v = 0.f;
    #pragma unroll
    for (int i = 0; i < 4; ++i) {
        float4 x = n4[threadIdx.x + 1024 * i];
        v = fmaxf(fmaxf(fabsf(x.x), fabsf(x.y)), fmaxf(fmaxf(fabsf(x.z), fabsf(x.w)), v));
    }
    #pragma unroll
    for (int o = 32; o; o >>= 1) v = fmaxf(v, __shfl_xor(v, o));
    __shared__ float sb[16];
    if ((threadIdx.x & 63) == 0) sb[threadIdx.x >> 6] = v;
    __syncthreads();
    if (threadIdx.x == 0) {
        float m = sb[0];
        #pragma unroll
        for (int i = 1; i < 16; ++i) m = fmaxf(m, sb[i]);
        g_maxabs = m;
    }
}

// blocks: 0-19 mag rows, 20-35 scale rows, 36-83 ctx rows, 84-255 zero pad rows,
// 256-2559 weight cast (in_proj_w + out_proj_w -> bf16).
__global__ void k_tables(const float* __restrict__ mag_emb,
                         const float* __restrict__ se_w1, const float* __restrict__ se_b1,
                         const float* __restrict__ se_g1, const float* __restrict__ se_bt1,
                         const float* __restrict__ se_w2, const float* __restrict__ se_b2,
                         const float* __restrict__ ce_w, const float* __restrict__ ce_b,
                         const float* __restrict__ ce_g, const float* __restrict__ ce_bt,
                         const float* __restrict__ in_proj_w, const float* __restrict__ out_proj_w) {
    __shared__ float sbuf[4];
    __shared__ float sh[192];
    const int t = threadIdx.x;
    const int blk = blockIdx.x;
    if (blk < 20) {
        #pragma unroll
        for (int i = 0; i < 3; ++i) {
            int d = t + 256 * i;
            g_Abf[(size_t)(BB + blk) * DD + d] = (short)f2bf(mag_emb[blk * DD + d]);
        }
    } else if (blk < 36) {
        int sfi = blk - 20;
        float sf = (float)(sfi - 10);
        float pre = 0.f;
        if (t < 192) pre = sf * se_w1[t] + se_b1[t];
        float s = block_sum256(t < 192 ? pre : 0.f, sbuf);
        float m = s / 192.f;
        float dd = (t < 192) ? (pre - m) : 0.f;
        float vv = block_sum256(dd * dd, sbuf);
        float inv = 1.f / sqrtf(vv / 192.f + 1e-5f);
        if (t < 192) sh[t] = gelu_exact((pre - m) * inv * se_g1[t] + se_bt1[t]);
        __syncthreads();
        #pragma unroll
        for (int i = 0; i < 3; ++i) {
            int d = t + 256 * i;
            float acc = se_b2[d];
            for (int j = 0; j < 192; ++j) acc += se_w2[d * 192 + j] * sh[j];
            g_Abf[(size_t)(BB + 20 + sfi) * DD + d] = (short)f2bf(acc);
        }
    } else if (blk < 84) {
        int c = blk - 36;
        int si = c >> 4, sfi = c & 15;
        float f0 = (float)(si - 1);
        float f1 = (float)(sfi - 10) / 16.f;
        float pre[3];
        float ps = 0.f;
        #pragma unroll
        for (int i = 0; i < 3; ++i) {
            int d = t + 256 * i;
            pre[i] = f0 * ce_w[2 * d] + f1 * ce_w[2 * d + 1] + ce_b[d];
            ps += pre[i];
        }
        float s = block_sum256(ps, sbuf);
        float m = s / 768.f;
        float qs = 0.f;
        #pragma unroll
        for (int i = 0; i < 3; ++i) { float dd = pre[i] - m; qs += dd * dd; }
        float vv = block_sum256(qs, sbuf);
        float inv = 1.f / sqrtf(vv / 768.f + 1e-5f);
        #pragma unroll
        for (int i = 0; i < 3; ++i) {
            int d = t + 256 * i;
            g_Abf[(size_t)(BB + 36 + c) * DD + d] =
                (short)f2bf(gelu_exact((pre[i] - m) * inv * ce_g[d] + ce_bt[d]));
        }
    } else if (blk < 256) {
        int row = BB + 84 + (blk - 84);    // 16468 .. 16639
        #pragma unroll
        for (int i = 0; i < 3; ++i) g_Abf[(size_t)row * DD + t + 256 * i] = 0;
    } else {
        int i = (blk - 256) * 256 + t;
        const bool second = (i >= 442368);
        const float* src = second ? out_proj_w : in_proj_w;
        short* dst = second ? g_WoutBf : g_W;
        int j = second ? (i - 442368) : i;
        const float4 v = *reinterpret_cast<const float4*>(&src[(size_t)j * 4]);
        ushort4 o;
        o.x = f2bf(v.x); o.y = f2bf(v.y); o.z = f2bf(v.z); o.w = f2bf(v.w);
        *reinterpret_cast<ushort4*>(&dst[(size_t)j * 4]) = o;
    }
}

// one wave per element: num_enc row (fp32 math, bf16 store)
__global__ void k_numenc(const float* __restrict__ number,
                         const float* __restrict__ ne_w, const float* __restrict__ ne_b,
                         const float* __restrict__ ne_g, const float* __restrict__ ne_bt) {
    const int wid = threadIdx.x >> 6, lane = threadIdx.x & 63;
    const int e = blockIdx.x * 4 + wid;
    const float ma = g_maxabs;
    const float x = number[e];
    const float a = x / (ma + 1e-10f);
    const float b = log1pf(fabsf(x)) / (log1pf(ma) + 1e-10f);
    float pre[12];
    float s = 0.f;
    #pragma unroll
    for (int j = 0; j < 12; ++j) {
        int d = lane + 64 * j;
        float2 w = *reinterpret_cast<const float2*>(&ne_w[2 * d]);
        pre[j] = a * w.x + b * w.y + ne_b[d];
        s += pre[j];
    }
    #pragma unroll
    for (int o = 32; o; o >>= 1) s += __shfl_xor(s, o);
    float m = s / 768.f;
    float q = 0.f;
    #pragma unroll
    for (int j = 0; j < 12; ++j) { float dd = pre[j] - m; q += dd * dd; }
    #pragma unroll
    for (int o = 32; o; o >>= 1) q += __shfl_xor(q, o);
    float inv = 1.f / sqrtf(q / 768.f + 1e-5f);
    #pragma unroll
    for (int j = 0; j < 12; ++j) {
        int d = lane + 64 * j;
        g_Abf[(size_t)e * DD + d] = (short)f2bf(gelu_exact((pre[j] - m) * inv * ne_g[d] + ne_bt[d]));
    }
}

// GEMM1 (R7 winner restored): C[m][n] = sum_k A[m][k] * B[n][k], A=g_Abf (M=16640),
// B=g_W, C=g_qkv. 128x128 tile, BK=64, 512 thr / 8 waves, wave-tile 64x32 (acc 32
// VGPR -> high occupancy). 1-phase, 32KB LDS. gload_lds width-16 linear-dest +
// inverse-swizzled source, 8-slot XOR swizzle on read. Bijective XCD swizzle.
__global__ __launch_bounds__(512) void gemm1(int N, int K) {
    const short* A = g_Abf;
    const short* B = g_W;
    short* C = g_qkv;

    __shared__ short As[128 * 64];
    __shared__ short Bs[128 * 64];
    const int t = threadIdx.x;

    const int GX = gridDim.x;
    const int nwg = GX * gridDim.y;
    const int lin = blockIdx.y * GX + blockIdx.x;
    const int qq = nwg >> 3, rr = nwg & 7;
    const int xcd = lin & 7, idx = lin >> 3;
    const int nl = (xcd < rr ? xcd * (qq + 1) : rr * (qq + 1) + (xcd - rr) * qq) + idx;
    const int m0 = (nl / GX) * 128, n0 = (nl % GX) * 128;

    const int wid = t >> 6, lane = t & 63;
    const int wm = wid >> 2, wn = wid & 3;
    const int fr = lane & 15, ks = lane >> 4;

    f32x4 acc[4][2];
    #pragma unroll
    for (int m = 0; m < 4; ++m)
        #pragma unroll
        for (int n = 0; n < 2; ++n) acc[m][n] = (f32x4){0.f, 0.f, 0.f, 0.f};

    for (int k0 = 0; k0 < K; k0 += 64) {
        #pragma unroll
        for (int i = 0; i < 2; ++i) {
            int L = t + 512 * i;
            int row = L >> 3, sp = L & 7;
            int s = sp ^ (row & 7);
            const short* srcA = A + (size_t)(m0 + row) * K + k0 + s * 8;
            const short* srcB = B + (size_t)(n0 + row) * K + k0 + s * 8;
            __builtin_amdgcn_global_load_lds(
                (const __attribute__((address_space(1))) unsigned int*)srcA,
                (__attribute__((address_space(3))) unsigned int*)((char*)As + L * 16), 16, 0, 0);
            __builtin_amdgcn_global_load_lds(
                (const __attribute__((address_space(1))) unsigned int*)srcB,
                (__attribute__((address_space(3))) unsigned int*)((char*)Bs + L * 16), 16, 0, 0);
        }
        __syncthreads();
        #pragma unroll
        for (int kk = 0; kk < 2; ++kk) {
            bf16x8 af[4], bfr[2];
            #pragma unroll
            for (int m = 0; m < 4; ++m) {
                int row = wm * 64 + m * 16 + fr;
                int off = row * 128 + ((((kk << 2) | ks) ^ (row & 7)) * 16);
                af[m] = *(const bf16x8*)((const char*)As + off);
            }
            #pragma unroll
            for (int n = 0; n < 2; ++n) {
                int row = wn * 32 + n * 16 + fr;
                int off = row * 128 + ((((kk << 2) | ks) ^ (row & 7)) * 16);
                bfr[n] = *(const bf16x8*)((const char*)Bs + off);
            }
            #pragma unroll
            for (int m = 0; m < 4; ++m)
                #pragma unroll
                for (int n = 0; n < 2; ++n)
                    acc[m][n] = __builtin_amdgcn_mfma_f32_16x16x32_bf16(af[m], bfr[n], acc[m][n], 0, 0, 0);
        }
        __syncthreads();
    }

    #pragma unroll
    for (int m = 0; m < 4; ++m)
        #pragma unroll
        for (int n = 0; n < 2; ++n)
            #pragma unroll
            for (int j = 0; j < 4; ++j) {
                int row = m0 + wm * 64 + m * 16 + (lane >> 4) * 4 + j;
                int col = n0 + wn * 32 + n * 16 + fr;
                C[(size_t)row * N + col] = (short)f2bf(acc[m][n][j]);
            }
}

// FUSED: attn-mix (V-space) -> out-projection GEMM -> softplus scale -> L2 norm.
// One block = 32 batch rows, 512 threads / 8 waves.
// Phase 0: per-wave mix of 4 rows -> LDS A[32][776] bf16 (pad: 2-way banks, free)
//          + per-row softplus scale -> sc_lds.
// Phase 1: C[32][768] = A @ Wout^T over K=768 in 24 steps of 32. Wave-tile 32x96
//          (acc 2x6 f32x4 = 48 VGPR). Wout K-panel staged to LDS[768][40] (pad,
//          16B-aligned rows) via reg-staging with issue-early/write-late (T14):
//          next panel's 6 global loads issued before compute, ds_write after the
//          barrier — HBM latency hides under the 12-MFMA compute.
// Epilogue: bias + sc + NaN guard in-register, cross-wave row-norm via LDS,
//          write final fp32 output directly.
__global__ __launch_bounds__(512, 2) void k_fused(const float* __restrict__ number,
                                                  const float* __restrict__ boundaries,
                                                  const float* __restrict__ in_proj_b,
                                                  const float* __restrict__ out_proj_b,
                                                  const float* __restrict__ ms,
                                                  const float* __restrict__ temp,
                                                  float* __restrict__ out) {
    __shared__ short A_lds[FB * 776];          // 49,664 B (row stride 1552 B, 16B-aligned)
    __shared__ short B_lds[768 * 40];          // 61,440 B (row stride 80 B, 16B-aligned)
    __shared__ float ss_lds[8][FB];
    __shared__ float sc_lds[FB];
    __shared__ float inv_lds[FB];

    const int t = threadIdx.x;
    const int wid = t >> 6, lane = t & 63;
    const int b = blockIdx.x;
    const int d0 = lane * 12;

    // ---------------- phase 0: attention mix for 4 rows per wave ----------------
    float bq[12], bk[12], bv[12];
    #pragma unroll
    for (int c4 = 0; c4 < 3; ++c4) {
        float4 a = *reinterpret_cast<const float4*>(&in_proj_b[d0 + c4 * 4]);
        float4 bb = *reinterpret_cast<const float4*>(&in_proj_b[768 + d0 + c4 * 4]);
        float4 c = *reinterpret_cast<const float4*>(&in_proj_b[1536 + d0 + c4 * 4]);
        bq[c4 * 4 + 0] = a.x; bq[c4 * 4 + 1] = a.y; bq[c4 * 4 + 2] = a.z; bq[c4 * 4 + 3] = a.w;
        bk[c4 * 4 + 0] = bb.x; bk[c4 * 4 + 1] = bb.y; bk[c4 * 4 + 2] = bb.z; bk[c4 * 4 + 3] = bb.w;
        bv[c4 * 4 + 0] = c.x; bv[c4 * 4 + 1] = c.y; bv[c4 * 4 + 2] = c.z; bv[c4 * 4 + 3] = c.w;
    }
    for (int rr = 0; rr < 4; ++rr) {
        const int rloc = wid * 4 + rr;
        const int e = b * FB + rloc;
        const float x = number[e];
        int bin = 0;
        #pragma unroll
        for (int j = 0; j < 20; ++j) bin += (boundaries[j] < x) ? 1 : 0;
        bin = min(bin, 19);
        float sf = floorf(log10f(fabsf(x) + 1e-10f));
        int sfi = min(max((int)sf + 10, 0), 15);
        int si = (x > 0.f) ? 2 : ((x < 0.f) ? 0 : 1);
        int rows[4] = {e, BB + bin, BB + 20 + sfi, BB + 36 + si * 16 + sfi};

        float q[4][12], k[4][12], v[4][12];
        #pragma unroll
        for (int i = 0; i < 4; ++i) {
            const unsigned short* base = (const unsigned short*)&g_qkv[(size_t)rows[i] * 2304 + d0];
            #pragma unroll
            for (int c4 = 0; c4 < 3; ++c4) {
                ushort4 uq = *reinterpret_cast<const ushort4*>(base + c4 * 4);
                ushort4 uk = *reinterpret_cast<const ushort4*>(base + 768 + c4 * 4);
                ushort4 uv = *reinterpret_cast<const ushort4*>(base + 1536 + c4 * 4);
                q[i][c4 * 4 + 0] = bf2f(uq.x) + bq[c4 * 4 + 0];
                q[i][c4 * 4 + 1] = bf2f(uq.y) + bq[c4 * 4 + 1];
                q[i][c4 * 4 + 2] = bf2f(uq.z) + bq[c4 * 4 + 2];
                q[i][c4 * 4 + 3] = bf2f(uq.w) + bq[c4 * 4 + 3];
                k[i][c4 * 4 + 0] = bf2f(uk.x) + bk[c4 * 4 + 0];
                k[i][c4 * 4 + 1] = bf2f(uk.y) + bk[c4 * 4 + 1];
                k[i][c4 * 4 + 2] = bf2f(uk.z) + bk[c4 * 4 + 2];
                k[i][c4 * 4 + 3] = bf2f(uk.w) + bk[c4 * 4 + 3];
                v[i][c4 * 4 + 0] = bf2f(uv.x) + bv[c4 * 4 + 0];
                v[i][c4 * 4 + 1] = bf2f(uv.y) + bv[c4 * 4 + 1];
                v[i][c4 * 4 + 2] = bf2f(uv.z) + bv[c4 * 4 + 2];
                v[i][c4 * 4 + 3] = bf2f(uv.w) + bv[c4 * 4 + 3];
            }
        }
        const float isq = 0.1020620726159658f;   // 1/sqrt(96)
        float s[4][4];
        #pragma unroll
        for (int i = 0; i < 4; ++i)
            #pragma unroll
            for (int j = 0; j < 4; ++j) {
                float p = 0.f;
                #pragma unroll
                for (int c = 0; c < 12; ++c) p += q[i][c] * k[j][c];
                p += __shfl_xor(p, 1);
                p += __shfl_xor(p, 2);
                p += __shfl_xor(p, 4);
                s[i][j] = p * isq;
            }
        const float wt[4] = {0.4f, 0.3f, 0.2f, 0.1f};
        float wtil[4] = {0.f, 0.f, 0.f, 0.f};
        #pragma unroll
        for (int i = 0; i < 4; ++i) {
            float mx = fmaxf(fmaxf(s[i][0], s[i][1]), fmaxf(s[i][2], s[i][3]));
            float ex[4], den = 0.f;
            #pragma unroll
            for (int j = 0; j < 4; ++j) { ex[j] = __expf(s[i][j] - mx); den += ex[j]; }
            float idn = wt[i] / den;
            #pragma unroll
            for (int j = 0; j < 4; ++j) wtil[j] += ex[j] * idn;
        }
        unsigned short ob[12];
        #pragma unroll
        for (int c = 0; c < 12; ++c) {
            float o = wtil[0] * v[0][c] + wtil[1] * v[1][c] + wtil[2] * v[2][c] + wtil[3] * v[3][c];
            ob[c] = f2bf(o);
        }
        char* abase = (char*)A_lds + rloc * 1552 + lane * 24;
        #pragma unroll
        for (int c4 = 0; c4 < 3; ++c4)
            *reinterpret_cast<ushort4*>(abase + c4 * 8) =
                make_ushort4(ob[c4 * 4 + 0], ob[c4 * 4 + 1], ob[c4 * 4 + 2], ob[c4 * 4 + 3]);
        if (lane == 0) {
            float z = ms[bin] / temp[0];
            sc_lds[rloc] = (z > 20.f) ? z : log1pf(expf(z));
        }
    }
    __syncthreads();

    // ---------------- phase 1: GEMM 32x768 = A[32][768] @ Wout^T ----------------
    const int fr = lane & 15, ks = lane >> 4;
    const int wn = wid;                        // 8 waves x 96 cols = 768
    f32x4 acc[2][6];
    #pragma unroll
    for (int m = 0; m < 2; ++m)
        #pragma unroll
        for (int n = 0; n < 6; ++n) acc[m][n] = (f32x4){0.f, 0.f, 0.f, 0.f};

    bf16x8 stg[6];
    // prologue: stage panel 0
    #pragma unroll
    for (int i = 0; i < 6; ++i) {
        int c = t + 512 * i;
        int row = c >> 2, sl = c & 3;
        stg[i] = *(const bf16x8*)(g_WoutBf + (size_t)row * 768 + sl * 8);
    }
    #pragma unroll
    for (int i = 0; i < 6; ++i) {
        int c = t + 512 * i;
        int row = c >> 2, sl = c & 3;
        *(bf16x8*)((char*)B_lds + row * 80 + sl * 16) = stg[i];
    }
    __syncthreads();

    for (int s = 0; s < 24; ++s) {
        if (s < 23) {
            int k0n = (s + 1) * 32;
            #pragma unroll
            for (int i = 0; i < 6; ++i) {
                int c = t + 512 * i;
                int row = c >> 2, sl = c & 3;
                stg[i] = *(const bf16x8*)(g_WoutBf + (size_t)row * 768 + k0n + sl * 8);
            }
        }
        // compute step s (panel s is in B_lds)
        bf16x8 af[2], bf6[6];
        #pragma unroll
        for (int m = 0; m < 2; ++m)
            af[m] = *(const bf16x8*)((const char*)A_lds + (m * 16 + fr) * 1552 + s * 64 + ks * 16);
        #pragma unroll
        for (int n = 0; n < 6; ++n)
            bf6[n] = *(const bf16x8*)((const char*)B_lds + (wn * 96 + n * 16 + fr) * 80 + ks * 16);
        #pragma unroll
        for (int m = 0; m < 2; ++m)
            #pragma unroll
            for (int n = 0; n < 6; ++n)
                acc[m][n] = __builtin_amdgcn_mfma_f32_16x16x32_bf16(af[m], bf6[n], acc[m][n], 0, 0, 0);
        if (s < 23) {
            __syncthreads();                    // all waves done reading panel s; loads drained
            #pragma unroll
            for (int i = 0; i < 6; ++i) {
                int c = t + 512 * i;
                int row = c >> 2, sl = c & 3;
                *(bf16x8*)((char*)B_lds + row * 80 + sl * 16) = stg[i];
            }
            __syncthreads();                    // panel s+1 visible
        }
    }

    // ---------------- epilogue: bias + scale + nan + L2 norm ----------------
    float bias[6];
    #pragma unroll
    for (int n = 0; n < 6; ++n) bias[n] = out_proj_b[wn * 96 + n * 16 + fr];
    float part[2][4];
    #pragma unroll
    for (int m = 0; m < 2; ++m)
        #pragma unroll
        for (int j = 0; j < 4; ++j) part[m][j] = 0.f;
    #pragma unroll
    for (int m = 0; m < 2; ++m)
        #pragma unroll
        for (int j = 0; j < 4; ++j) {
            int row = m * 16 + ks * 4 + j;
            float sc = sc_lds[row];
            #pragma unroll
            for (int n = 0; n < 6; ++n) {
                float p = (acc[m][n][j] + bias[n]) * sc;
                if (p != p) p = 0.f;
                acc[m][n][j] = p;
                part[m][j] += p * p;
            }
        }
    #pragma unroll
    for (int m = 0; m < 2; ++m)
        #pragma unroll
        for (int j = 0; j < 4; ++j) {
            float v = part[m][j];
            v += __shfl_xor(v, 1);
            v += __shfl_xor(v, 2);
            v += __shfl_xor(v, 4);
            v += __shfl_xor(v, 8);
            part[m][j] = v;
        }
    if (fr == 0) {
        #pragma unroll
        for (int m = 0; m < 2; ++m)
            #pragma unroll
            for (int j = 0; j < 4; ++j) ss_lds[wid][m * 16 + ks * 4 + j] = part[m][j];
    }
    __syncthreads();
    if (t < FB) {
        float s2 = 0.f;
        #pragma unroll
        for (int w = 0; w < 8; ++w) s2 += ss_lds[w][t];
        inv_lds[t] = 1.f / fmaxf(sqrtf(s2), 1e-12f);
    }
    __syncthreads();
    #pragma unroll
    for (int m = 0; m < 2; ++m)
        #pragma unroll
        for (int j = 0; j < 4; ++j) {
            int row = m * 16 + ks * 4 + j;
            float inv = inv_lds[row];
            size_t obase = (size_t)(b * FB + row) * DD;
            #pragma unroll
            for (int n = 0; n < 6; ++n)
                out[obase + wn * 96 + n * 16 + fr] = acc[m][n][j] * inv;
        }
}

extern "C" void kernel_launch(void* const* d_in, const int* in_sizes, int n_in,
                              void* d_out, int out_size, void* d_ws, size_t ws_size,
                              hipStream_t stream) {
    const float* number      = (const float*)d_in[0];
    const float* boundaries  = (const float*)d_in[1];
    const float* mag_emb     = (const float*)d_in[2];
    const float* se_w1       = (const float*)d_in[3];
    const float* se_b1       = (const float*)d_in[4];
    const float* se_g1       = (const float*)d_in[5];
    const float* se_bt1      = (const float*)d_in[6];
    const float* se_w2       = (const float*)d_in[7];
    const float* se_b2       = (const float*)d_in[8];
    const float* ne_w        = (const float*)d_in[9];
    const float* ne_b        = (const float*)d_in[10];
    const float* ne_g        = (const float*)d_in[11];
    const float* ne_bt       = (const float*)d_in[12];
    const float* ce_w        = (const float*)d_in[13];
    const float* ce_b        = (const float*)d_in[14];
    const float* ce_g        = (const float*)d_in[15];
    const float* ce_bt       = (const float*)d_in[16];
    const float* in_proj_w   = (const float*)d_in[17];
    const float* in_proj_b   = (const float*)d_in[18];
    const float* out_proj_w  = (const float*)d_in[19];
    const float* out_proj_b  = (const float*)d_in[20];
    const float* mag_scale   = (const float*)d_in[21];
    const float* temperature = (const float*)d_in[22];
    float* out = (float*)d_out;

    k_absmax<<<1, 1024, 0, stream>>>(number);
    k_tables<<<2560, 256, 0, stream>>>(mag_emb, se_w1, se_b1, se_g1, se_bt1, se_w2, se_b2,
                                       ce_w, ce_b, ce_g, ce_bt, in_proj_w, out_proj_w);
    k_numenc<<<BB / 4, 256, 0, stream>>>(number, ne_w, ne_b, ne_g, ne_bt);
    gemm1<<<dim3(2304 / 128, MPAD / 128), 512, 0, stream>>>(2304, DD);
    k_fused<<<BB / FB, 512, 0, stream>>>(number, boundaries, in_proj_b, out_proj_b,
                                         mag_scale, temperature, out);
}

// Round 10
// 224.203 us; speedup vs baseline: 1.1382x; 1.1382x over previous
//
#include <hip/hip_runtime.h>
#include <hip/hip_bf16.h>
#include <math.h>

#define BB 16384
#define DD 768
#define MPAD 16640             // 16384 + 84 table rows + zero pad to 65*256

typedef __attribute__((ext_vector_type(8))) short bf16x8;
typedef __attribute__((ext_vector_type(4))) float f32x4;

// Static device scratch — referenced ONLY from device code.
__device__ short g_Abf[(size_t)MPAD * DD];          // bf16 feats
__device__ short g_W[(size_t)2304 * DD];            // bf16 in_proj_w (Wq|Wk|Wv rows)
__device__ short g_WoutBf[(size_t)DD * DD];         // bf16 out_proj_w
__device__ short g_qkv[(size_t)MPAD * 2304];        // bf16 GEMM1 out: q|k|v per row (no bias)
__device__ short g_mixed[(size_t)BB * DD];          // bf16 attention-mixed v (+bias)
__device__ short g_pre[(size_t)BB * DD];            // bf16 GEMM2 out (no bias)
__device__ float g_maxabs;

__device__ inline unsigned short f2bf(float x) {
    union { float f; unsigned u; } v; v.f = x;
    unsigned r = v.u + 0x7fffu + ((v.u >> 16) & 1u);
    return (unsigned short)(r >> 16);
}
__device__ inline float bf2f(unsigned short h) {
    union { unsigned u; float f; } v; v.u = ((unsigned)h) << 16;
    return v.f;
}

__device__ inline float gelu_exact(float x) {
    return 0.5f * x * (1.0f + erff(x * 0.70710678118654752440f));
}

__device__ inline float block_sum256(float v, float* sbuf) {
    #pragma unroll
    for (int o = 32; o; o >>= 1) v += __shfl_xor(v, o);
    __syncthreads();
    if ((threadIdx.x & 63) == 0) sbuf[threadIdx.x >> 6] = v;
    __syncthreads();
    return sbuf[0] + sbuf[1] + sbuf[2] + sbuf[3];
}

// single block, 1024 threads: max|x| -> g_maxabs
__global__ __launch_bounds__(1024) void k_absmax(const float* __restrict__ number) {
    const float4* n4 = reinterpret_cast<const float4*>(number);
    float v = 0.f;
    #pragma unroll
    for (int i = 0; i < 4; ++i) {
        float4 x = n4[threadIdx.x + 1024 * i];
        v = fmaxf(fmaxf(fabsf(x.x), fabsf(x.y)), fmaxf(fmaxf(fabsf(x.z), fabsf(x.w)), v));
    }
    #pragma unroll
    for (int o = 32; o; o >>= 1) v = fmaxf(v, __shfl_xor(v, o));
    __shared__ float sb[16];
    if ((threadIdx.x & 63) == 0) sb[threadIdx.x >> 6] = v;
    __syncthreads();
    if (threadIdx.x == 0) {
        float m = sb[0];
        #pragma unroll
        for (int i = 1; i < 16; ++i) m = fmaxf(m, sb[i]);
        g_maxabs = m;
    }
}

// blocks: 0-19 mag rows, 20-35 scale rows, 36-83 ctx rows, 84-255 zero pad rows,
// 256-2559 weight cast (in_proj_w + out_proj_w -> bf16).
__global__ void k_tables(const float* __restrict__ mag_emb,
                         const float* __restrict__ se_w1, const float* __restrict__ se_b1,
                         const float* __restrict__ se_g1, const float* __restrict__ se_bt1,
                         const float* __restrict__ se_w2, const float* __restrict__ se_b2,
                         const float* __restrict__ ce_w, const float* __restrict__ ce_b,
                         const float* __restrict__ ce_g, const float* __restrict__ ce_bt,
                         const float* __restrict__ in_proj_w, const float* __restrict__ out_proj_w) {
    __shared__ float sbuf[4];
    __shared__ float sh[192];
    const int t = threadIdx.x;
    const int blk = blockIdx.x;
    if (blk < 20) {
        #pragma unroll
        for (int i = 0; i < 3; ++i) {
            int d = t + 256 * i;
            g_Abf[(size_t)(BB + blk) * DD + d] = (short)f2bf(mag_emb[blk * DD + d]);
        }
    } else if (blk < 36) {
        int sfi = blk - 20;
        float sf = (float)(sfi - 10);
        float pre = 0.f;
        if (t < 192) pre = sf * se_w1[t] + se_b1[t];
        float s = block_sum256(t < 192 ? pre : 0.f, sbuf);
        float m = s / 192.f;
        float dd = (t < 192) ? (pre - m) : 0.f;
        float vv = block_sum256(dd * dd, sbuf);
        float inv = 1.f / sqrtf(vv / 192.f + 1e-5f);
        if (t < 192) sh[t] = gelu_exact((pre - m) * inv * se_g1[t] + se_bt1[t]);
        __syncthreads();
        #pragma unroll
        for (int i = 0; i < 3; ++i) {
            int d = t + 256 * i;
            float acc = se_b2[d];
            for (int j = 0; j < 192; ++j) acc += se_w2[d * 192 + j] * sh[j];
            g_Abf[(size_t)(BB + 20 + sfi) * DD + d] = (short)f2bf(acc);
        }
    } else if (blk < 84) {
        int c = blk - 36;
        int si = c >> 4, sfi = c & 15;
        float f0 = (float)(si - 1);
        float f1 = (float)(sfi - 10) / 16.f;
        float pre[3];
        float ps = 0.f;
        #pragma unroll
        for (int i = 0; i < 3; ++i) {
            int d = t + 256 * i;
            pre[i] = f0 * ce_w[2 * d] + f1 * ce_w[2 * d + 1] + ce_b[d];
            ps += pre[i];
        }
        float s = block_sum256(ps, sbuf);
        float m = s / 768.f;
        float qs = 0.f;
        #pragma unroll
        for (int i = 0; i < 3; ++i) { float dd = pre[i] - m; qs += dd * dd; }
        float vv = block_sum256(qs, sbuf);
        float inv = 1.f / sqrtf(vv / 768.f + 1e-5f);
        #pragma unroll
        for (int i = 0; i < 3; ++i) {
            int d = t + 256 * i;
            g_Abf[(size_t)(BB + 36 + c) * DD + d] =
                (short)f2bf(gelu_exact((pre[i] - m) * inv * ce_g[d] + ce_bt[d]));
        }
    } else if (blk < 256) {
        int row = BB + 84 + (blk - 84);    // 16468 .. 16639
        #pragma unroll
        for (int i = 0; i < 3; ++i) g_Abf[(size_t)row * DD + t + 256 * i] = 0;
    } else {
        int i = (blk - 256) * 256 + t;
        const bool second = (i >= 442368);
        const float* src = second ? out_proj_w : in_proj_w;
        short* dst = second ? g_WoutBf : g_W;
        int j = second ? (i - 442368) : i;
        const float4 v = *reinterpret_cast<const float4*>(&src[(size_t)j * 4]);
        ushort4 o;
        o.x = f2bf(v.x); o.y = f2bf(v.y); o.z = f2bf(v.z); o.w = f2bf(v.w);
        *reinterpret_cast<ushort4*>(&dst[(size_t)j * 4]) = o;
    }
}

// one wave per element: num_enc row (fp32 math, bf16 store)
__global__ void k_numenc(const float* __restrict__ number,
                         const float* __restrict__ ne_w, const float* __restrict__ ne_b,
                         const float* __restrict__ ne_g, const float* __restrict__ ne_bt) {
    const int wid = threadIdx.x >> 6, lane = threadIdx.x & 63;
    const int e = blockIdx.x * 4 + wid;
    const float ma = g_maxabs;
    const float x = number[e];
    const float a = x / (ma + 1e-10f);
    const float b = log1pf(fabsf(x)) / (log1pf(ma) + 1e-10f);
    float pre[12];
    float s = 0.f;
    #pragma unroll
    for (int j = 0; j < 12; ++j) {
        int d = lane + 64 * j;
        float2 w = *reinterpret_cast<const float2*>(&ne_w[2 * d]);
        pre[j] = a * w.x + b * w.y + ne_b[d];
        s += pre[j];
    }
    #pragma unroll
    for (int o = 32; o; o >>= 1) s += __shfl_xor(s, o);
    float m = s / 768.f;
    float q = 0.f;
    #pragma unroll
    for (int j = 0; j < 12; ++j) { float dd = pre[j] - m; q += dd * dd; }
    #pragma unroll
    for (int o = 32; o; o >>= 1) q += __shfl_xor(q, o);
    float inv = 1.f / sqrtf(q / 768.f + 1e-5f);
    #pragma unroll
    for (int j = 0; j < 12; ++j) {
        int d = lane + 64 * j;
        g_Abf[(size_t)e * DD + d] = (short)f2bf(gelu_exact((pre[j] - m) * inv * ne_g[d] + ne_bt[d]));
    }
}

// C[m][n] = sum_k A[m][k] * B[n][k]  (bf16 in/out, fp32 MFMA accum)
// which==0: A=g_Abf (M=16640), B=g_W,      C=g_qkv (N=2304)
// which==1: A=g_mixed (M=16384), B=g_WoutBf, C=g_pre (N=768)
// NEW SHAPE vs R7: 256x128 tile (MxN), BK=64, 512 thr / 8 waves arranged 4Mx2N,
// wave-tile 64x64 -> acc 4x4 f32x4 = 64 VGPR, __launch_bounds__(512,4) caps VGPR
// at 128 -> 4 waves/SIMD (2 blocks/CU). 32 MFMA per wave per K-step (2x R7) =
// ~620 MFMA-cycles per SIMD per barrier window — doubles matrix-pipe coverage
// at the same occupancy; barriers per unit work halved; better B reuse.
// 1-phase, 48KB LDS, gload_lds w16 linear-dest + inverse-swizzled source,
// 8-slot XOR swizzle on read. Bijective XCD swizzle.
__global__ __launch_bounds__(512, 4) void gemm_bt(int which, int N, int K) {
    const short* A = (which == 0) ? g_Abf : g_mixed;
    const short* B = (which == 0) ? g_W : g_WoutBf;
    short* C = (which == 0) ? g_qkv : g_pre;

    __shared__ short As[256 * 64];             // 32 KB
    __shared__ short Bs[128 * 64];             // 16 KB
    const int t = threadIdx.x;

    const int GX = gridDim.x;
    const int nwg = GX * gridDim.y;
    const int lin = blockIdx.y * GX + blockIdx.x;
    const int qq = nwg >> 3, rr = nwg & 7;
    const int xcd = lin & 7, idx = lin >> 3;
    const int nl = (xcd < rr ? xcd * (qq + 1) : rr * (qq + 1) + (xcd - rr) * qq) + idx;
    const int m0 = (nl / GX) * 256, n0 = (nl % GX) * 128;

    const int wid = t >> 6, lane = t & 63;
    const int wm = wid >> 1, wn = wid & 1;      // 4 x 2 waves, wave tile 64x64
    const int fr = lane & 15, ks = lane >> 4;

    f32x4 acc[4][4];
    #pragma unroll
    for (int m = 0; m < 4; ++m)
        #pragma unroll
        for (int n = 0; n < 4; ++n) acc[m][n] = (f32x4){0.f, 0.f, 0.f, 0.f};

    for (int k0 = 0; k0 < K; k0 += 64) {
        // stage A: 256x64 = 2048 16B-slots, 4 issues/thread
        #pragma unroll
        for (int i = 0; i < 4; ++i) {
            int L = t + 512 * i;
            int row = L >> 3, sp = L & 7;
            int s = sp ^ (row & 7);
            const short* srcA = A + (size_t)(m0 + row) * K + k0 + s * 8;
            __builtin_amdgcn_global_load_lds(
                (const __attribute__((address_space(1))) unsigned int*)srcA,
                (__attribute__((address_space(3))) unsigned int*)((char*)As + L * 16), 16, 0, 0);
        }
        // stage B: 128x64 = 1024 slots, 2 issues/thread
        #pragma unroll
        for (int i = 0; i < 2; ++i) {
            int L = t + 512 * i;
            int row = L >> 3, sp = L & 7;
            int s = sp ^ (row & 7);
            const short* srcB = B + (size_t)(n0 + row) * K + k0 + s * 8;
            __builtin_amdgcn_global_load_lds(
                (const __attribute__((address_space(1))) unsigned int*)srcB,
                (__attribute__((address_space(3))) unsigned int*)((char*)Bs + L * 16), 16, 0, 0);
        }
        __syncthreads();
        #pragma unroll
        for (int kk = 0; kk < 2; ++kk) {
            bf16x8 af[4], bfr[4];
            #pragma unroll
            for (int m = 0; m < 4; ++m) {
                int row = wm * 64 + m * 16 + fr;
                int off = row * 128 + ((((kk << 2) | ks) ^ (row & 7)) * 16);
                af[m] = *(const bf16x8*)((const char*)As + off);
            }
            #pragma unroll
            for (int n = 0; n < 4; ++n) {
                int row = wn * 64 + n * 16 + fr;
                int off = row * 128 + ((((kk << 2) | ks) ^ (row & 7)) * 16);
                bfr[n] = *(const bf16x8*)((const char*)Bs + off);
            }
            #pragma unroll
            for (int m = 0; m < 4; ++m)
                #pragma unroll
                for (int n = 0; n < 4; ++n)
                    acc[m][n] = __builtin_amdgcn_mfma_f32_16x16x32_bf16(af[m], bfr[n], acc[m][n], 0, 0, 0);
        }
        __syncthreads();
    }

    #pragma unroll
    for (int m = 0; m < 4; ++m)
        #pragma unroll
        for (int n = 0; n < 4; ++n)
            #pragma unroll
            for (int j = 0; j < 4; ++j) {
                int row = m0 + wm * 64 + m * 16 + ks * 4 + j;
                int col = n0 + wn * 64 + n * 16 + fr;
                C[(size_t)row * N + col] = (short)f2bf(acc[m][n][j]);
            }
}

// fused attention + per-head mix IN V-SPACE. One wave per element; 12 dims/lane;
// head h = lane/8. Vectorized ushort4/float4 loads (G13).
__global__ void k_attn_mix(const float* __restrict__ number, const float* __restrict__ boundaries,
                           const float* __restrict__ in_proj_b) {
    const int wid = threadIdx.x >> 6, lane = threadIdx.x & 63;
    const int e = blockIdx.x * 4 + wid;
    const float x = number[e];
    int bin = 0;
    #pragma unroll
    for (int j = 0; j < 20; ++j) bin += (boundaries[j] < x) ? 1 : 0;
    bin = min(bin, 19);
    float sf = floorf(log10f(fabsf(x) + 1e-10f));
    int sfi = min(max((int)sf + 10, 0), 15);
    int si = (x > 0.f) ? 2 : ((x < 0.f) ? 0 : 1);
    int rows[4] = {e, BB + bin, BB + 20 + sfi, BB + 36 + si * 16 + sfi};

    const int d0 = lane * 12;
    float bq[12], bk[12], bv[12];
    #pragma unroll
    for (int c4 = 0; c4 < 3; ++c4) {
        float4 a = *reinterpret_cast<const float4*>(&in_proj_b[d0 + c4 * 4]);
        float4 b = *reinterpret_cast<const float4*>(&in_proj_b[768 + d0 + c4 * 4]);
        float4 c = *reinterpret_cast<const float4*>(&in_proj_b[1536 + d0 + c4 * 4]);
        bq[c4 * 4 + 0] = a.x; bq[c4 * 4 + 1] = a.y; bq[c4 * 4 + 2] = a.z; bq[c4 * 4 + 3] = a.w;
        bk[c4 * 4 + 0] = b.x; bk[c4 * 4 + 1] = b.y; bk[c4 * 4 + 2] = b.z; bk[c4 * 4 + 3] = b.w;
        bv[c4 * 4 + 0] = c.x; bv[c4 * 4 + 1] = c.y; bv[c4 * 4 + 2] = c.z; bv[c4 * 4 + 3] = c.w;
    }
    float q[4][12], k[4][12], v[4][12];
    #pragma unroll
    for (int i = 0; i < 4; ++i) {
        const unsigned short* base = (const unsigned short*)&g_qkv[(size_t)rows[i] * 2304 + d0];
        #pragma unroll
        for (int c4 = 0; c4 < 3; ++c4) {
            ushort4 uq = *reinterpret_cast<const ushort4*>(base + c4 * 4);
            ushort4 uk = *reinterpret_cast<const ushort4*>(base + 768 + c4 * 4);
            ushort4 uv = *reinterpret_cast<const ushort4*>(base + 1536 + c4 * 4);
            q[i][c4 * 4 + 0] = bf2f(uq.x) + bq[c4 * 4 + 0];
            q[i][c4 * 4 + 1] = bf2f(uq.y) + bq[c4 * 4 + 1];
            q[i][c4 * 4 + 2] = bf2f(uq.z) + bq[c4 * 4 + 2];
            q[i][c4 * 4 + 3] = bf2f(uq.w) + bq[c4 * 4 + 3];
            k[i][c4 * 4 + 0] = bf2f(uk.x) + bk[c4 * 4 + 0];
            k[i][c4 * 4 + 1] = bf2f(uk.y) + bk[c4 * 4 + 1];
            k[i][c4 * 4 + 2] = bf2f(uk.z) + bk[c4 * 4 + 2];
            k[i][c4 * 4 + 3] = bf2f(uk.w) + bk[c4 * 4 + 3];
            v[i][c4 * 4 + 0] = bf2f(uv.x) + bv[c4 * 4 + 0];
            v[i][c4 * 4 + 1] = bf2f(uv.y) + bv[c4 * 4 + 1];
            v[i][c4 * 4 + 2] = bf2f(uv.z) + bv[c4 * 4 + 2];
            v[i][c4 * 4 + 3] = bf2f(uv.w) + bv[c4 * 4 + 3];
        }
    }
    const float isq = 0.1020620726159658f;   // 1/sqrt(96)
    float s[4][4];
    #pragma unroll
    for (int i = 0; i < 4; ++i)
        #pragma unroll
        for (int j = 0; j < 4; ++j) {
            float p = 0.f;
            #pragma unroll
            for (int c = 0; c < 12; ++c) p += q[i][c] * k[j][c];
            p += __shfl_xor(p, 1);
            p += __shfl_xor(p, 2);
            p += __shfl_xor(p, 4);
            s[i][j] = p * isq;
        }
    const float wt[4] = {0.4f, 0.3f, 0.2f, 0.1f};
    float wtil[4] = {0.f, 0.f, 0.f, 0.f};
    #pragma unroll
    for (int i = 0; i < 4; ++i) {
        float mx = fmaxf(fmaxf(s[i][0], s[i][1]), fmaxf(s[i][2], s[i][3]));
        float ex[4], den = 0.f;
        #pragma unroll
        for (int j = 0; j < 4; ++j) { ex[j] = __expf(s[i][j] - mx); den += ex[j]; }
        float idn = wt[i] / den;
        #pragma unroll
        for (int j = 0; j < 4; ++j) wtil[j] += ex[j] * idn;
    }
    unsigned short ob[12];
    #pragma unroll
    for (int c = 0; c < 12; ++c) {
        float o = wtil[0] * v[0][c] + wtil[1] * v[1][c] + wtil[2] * v[2][c] + wtil[3] * v[3][c];
        ob[c] = f2bf(o);
    }
    unsigned short* mbase = (unsigned short*)&g_mixed[(size_t)e * DD + d0];
    #pragma unroll
    for (int c4 = 0; c4 < 3; ++c4)
        *reinterpret_cast<ushort4*>(mbase + c4 * 4) =
            make_ushort4(ob[c4 * 4 + 0], ob[c4 * 4 + 1], ob[c4 * 4 + 2], ob[c4 * 4 + 3]);
}

// one wave per row: add out-proj bias, softplus scale, nan guard, L2-normalize
__global__ void k_norm(const float* __restrict__ number, const float* __restrict__ boundaries,
                       const float* __restrict__ out_proj_b,
                       const float* __restrict__ ms, const float* __restrict__ temp,
                       float* __restrict__ out) {
    const int wid = threadIdx.x >> 6, lane = threadIdx.x & 63;
    const int e = blockIdx.x * 4 + wid;
    const float x = number[e];
    int bin = 0;
    #pragma unroll
    for (int j = 0; j < 20; ++j) bin += (boundaries[j] < x) ? 1 : 0;
    bin = min(bin, 19);
    float z = ms[bin] / temp[0];
    float sc = (z > 20.f) ? z : log1pf(expf(z));
    const int d0 = lane * 12;
    const unsigned short* base = (const unsigned short*)&g_pre[(size_t)e * DD + d0];
    float o[12], ss = 0.f;
    #pragma unroll
    for (int c4 = 0; c4 < 3; ++c4) {
        ushort4 u = *reinterpret_cast<const ushort4*>(base + c4 * 4);
        float4 b = *reinterpret_cast<const float4*>(&out_proj_b[d0 + c4 * 4]);
        float p0 = (bf2f(u.x) + b.x) * sc;
        float p1 = (bf2f(u.y) + b.y) * sc;
        float p2 = (bf2f(u.z) + b.z) * sc;
        float p3 = (bf2f(u.w) + b.w) * sc;
        if (p0 != p0) p0 = 0.f;
        if (p1 != p1) p1 = 0.f;
        if (p2 != p2) p2 = 0.f;
        if (p3 != p3) p3 = 0.f;
        o[c4 * 4 + 0] = p0; o[c4 * 4 + 1] = p1; o[c4 * 4 + 2] = p2; o[c4 * 4 + 3] = p3;
        ss += p0 * p0 + p1 * p1 + p2 * p2 + p3 * p3;
    }
    #pragma unroll
    for (int ofs = 32; ofs; ofs >>= 1) ss += __shfl_xor(ss, ofs);
    float inv = 1.f / fmaxf(sqrtf(ss), 1e-12f);
    float* obase = &out[(size_t)e * DD + d0];
    #pragma unroll
    for (int c4 = 0; c4 < 3; ++c4)
        *reinterpret_cast<float4*>(obase + c4 * 4) =
            make_float4(o[c4 * 4 + 0] * inv, o[c4 * 4 + 1] * inv, o[c4 * 4 + 2] * inv, o[c4 * 4 + 3] * inv);
}

extern "C" void kernel_launch(void* const* d_in, const int* in_sizes, int n_in,
                              void* d_out, int out_size, void* d_ws, size_t ws_size,
                              hipStream_t stream) {
    const float* number      = (const float*)d_in[0];
    const float* boundaries  = (const float*)d_in[1];
    const float* mag_emb     = (const float*)d_in[2];
    const float* se_w1       = (const float*)d_in[3];
    const float* se_b1       = (const float*)d_in[4];
    const float* se_g1       = (const float*)d_in[5];
    const float* se_bt1      = (const float*)d_in[6];
    const float* se_w2       = (const float*)d_in[7];
    const float* se_b2       = (const float*)d_in[8];
    const float* ne_w        = (const float*)d_in[9];
    const float* ne_b        = (const float*)d_in[10];
    const float* ne_g        = (const float*)d_in[11];
    const float* ne_bt       = (const float*)d_in[12];
    const float* ce_w        = (const float*)d_in[13];
    const float* ce_b        = (const float*)d_in[14];
    const float* ce_g        = (const float*)d_in[15];
    const float* ce_bt       = (const float*)d_in[16];
    const float* in_proj_w   = (const float*)d_in[17];
    const float* in_proj_b   = (const float*)d_in[18];
    const float* out_proj_w  = (const float*)d_in[19];
    const float* out_proj_b  = (const float*)d_in[20];
    const float* mag_scale   = (const float*)d_in[21];
    const float* temperature = (const float*)d_in[22];
    float* out = (float*)d_out;

    k_absmax<<<1, 1024, 0, stream>>>(number);
    k_tables<<<2560, 256, 0, stream>>>(mag_emb, se_w1, se_b1, se_g1, se_bt1, se_w2, se_b2,
                                       ce_w, ce_b, ce_g, ce_bt, in_proj_w, out_proj_w);
    k_numenc<<<BB / 4, 256, 0, stream>>>(number, ne_w, ne_b, ne_g, ne_bt);
    gemm_bt<<<dim3(2304 / 128, MPAD / 256), 512, 0, stream>>>(0, 2304, DD);
    k_attn_mix<<<BB / 4, 256, 0, stream>>>(number, boundaries, in_proj_b);
    gemm_bt<<<dim3(DD / 128, BB / 256), 512, 0, stream>>>(1, DD, DD);
    k_norm<<<BB / 4, 256, 0, stream>>>(number, boundaries, out_proj_b, mag_scale, temperature, out);
}